// Round 4
// baseline (815.057 us; speedup 1.0000x reference)
//
#include <hip/hip_runtime.h>
#include <hip/hip_bf16.h>
#include <cstdint>
#include <cstddef>

#define DIMC 1024
#define HEADS 16
#define HD 64
#define DFF 4096
#define BB 4
#define SS 4096
#define NROWS (BB*SS)   // 16384

typedef __bf16 bf16_t;
typedef __bf16 bf16x8 __attribute__((ext_vector_type(8)));
typedef __bf16 bf16x4 __attribute__((ext_vector_type(4)));
typedef float  f32x4  __attribute__((ext_vector_type(4)));

#define GLDS16(gp, lp) \
  __builtin_amdgcn_global_load_lds((const __attribute__((address_space(1))) void*)(gp), \
                                   (__attribute__((address_space(3))) void*)(lp), 16, 0, 0)

// ---------------------------------------------------------------- weight transpose f32[K][N] -> bf16[N][K]
__global__ __launch_bounds__(256) void wtrans(const float* __restrict__ W, bf16_t* __restrict__ Wt,
                                              int K, int N) {
  __shared__ float tile[32][33];
  int c0 = blockIdx.x * 32, r0 = blockIdx.y * 32;
  int tx = threadIdx.x, ty = threadIdx.y;
  #pragma unroll
  for (int i = 0; i < 32; i += 8)
    tile[ty + i][tx] = W[(long)(r0 + ty + i) * N + c0 + tx];
  __syncthreads();
  #pragma unroll
  for (int i = 0; i < 32; i += 8)
    Wt[(long)(c0 + ty + i) * K + r0 + tx] = (bf16_t)tile[tx][ty + i];
}

// ---------------------------------------------------------------- LayerNorm f32 row -> bf16 row
__global__ __launch_bounds__(256) void ln_kernel(const float* __restrict__ in,
                                                 const float* __restrict__ gamma,
                                                 const float* __restrict__ beta,
                                                 bf16_t* __restrict__ out) {
  long r = blockIdx.x;
  int t = threadIdx.x;
  float4 v = ((const float4*)(in + r * DIMC))[t];
  float s  = v.x + v.y + v.z + v.w;
  float sq = v.x * v.x + v.y * v.y + v.z * v.z + v.w * v.w;
  #pragma unroll
  for (int o = 32; o > 0; o >>= 1) { s += __shfl_xor(s, o); sq += __shfl_xor(sq, o); }
  __shared__ float red[8];
  if ((t & 63) == 0) { red[(t >> 6) * 2] = s; red[(t >> 6) * 2 + 1] = sq; }
  __syncthreads();
  s  = red[0] + red[2] + red[4] + red[6];
  sq = red[1] + red[3] + red[5] + red[7];
  float mu  = s * (1.0f / DIMC);
  float var = sq * (1.0f / DIMC) - mu * mu;
  float rs  = 1.0f / sqrtf(var + 1e-5f);
  float4 g  = ((const float4*)gamma)[t];
  float4 bb = ((const float4*)beta)[t];
  bf16x4 o;
  o[0] = (bf16_t)((v.x - mu) * rs * g.x + bb.x);
  o[1] = (bf16_t)((v.y - mu) * rs * g.y + bb.y);
  o[2] = (bf16_t)((v.z - mu) * rs * g.z + bb.z);
  o[3] = (bf16_t)((v.w - mu) * rs * g.w + bb.w);
  ((bf16x4*)(out + r * DIMC))[t] = o;
}

// ---------------------------------------------------------------- GEMM: A[M][K] bf16 @ Bt[N][K] bf16 -> epilogue
// MODE 0: bf16 out = acc + bias          MODE 1: f32 out = acc + bias + resid          MODE 2: bf16 out = gelu(acc+bias)
template <int MODE>
__global__ __launch_bounds__(256, 2) void gemm_bt(const bf16_t* __restrict__ A,
                                                  const bf16_t* __restrict__ Bt,
                                                  const float* __restrict__ bias,
                                                  const float* __restrict__ resid,
                                                  void* __restrict__ outp,
                                                  int M, int N, int K) {
  __shared__ bf16_t As[128 * 32];
  __shared__ bf16_t Bs[128 * 32];
  const int t = threadIdx.x;
  const int lane = t & 63;
  const int wave = t >> 6;
  const long arow0 = (long)blockIdx.y * 128;
  const long brow0 = (long)blockIdx.x * 128;
  const int wm = (wave >> 1) * 64, wn = (wave & 1) * 64;

  f32x4 acc[4][4] = {};
  const int c0 = t, c1 = t + 256;           // 16B chunks: row=c>>2, koff=(c&3)*8
  const int fr = lane & 15;
  const int kq = (lane >> 4) * 8;

  for (int kt = 0; kt < K; kt += 32) {
    {
      const bf16_t* ga0 = A  + (arow0 + (c0 >> 2)) * K + kt + (c0 & 3) * 8;
      const bf16_t* ga1 = A  + (arow0 + (c1 >> 2)) * K + kt + (c1 & 3) * 8;
      const bf16_t* gb0 = Bt + (brow0 + (c0 >> 2)) * K + kt + (c0 & 3) * 8;
      const bf16_t* gb1 = Bt + (brow0 + (c1 >> 2)) * K + kt + (c1 & 3) * 8;
      GLDS16(ga0, &As[c0 * 8]);
      GLDS16(ga1, &As[c1 * 8]);
      GLDS16(gb0, &Bs[c0 * 8]);
      GLDS16(gb1, &Bs[c1 * 8]);
    }
    asm volatile("s_waitcnt vmcnt(0)" ::: "memory");
    __syncthreads();
    bf16x8 a[4], b[4];
    #pragma unroll
    for (int i = 0; i < 4; ++i) {
      a[i] = *(const bf16x8*)&As[(wm + i * 16 + fr) * 32 + kq];
      b[i] = *(const bf16x8*)&Bs[(wn + i * 16 + fr) * 32 + kq];
    }
    #pragma unroll
    for (int i = 0; i < 4; ++i)
      #pragma unroll
      for (int j = 0; j < 4; ++j)
        acc[i][j] = __builtin_amdgcn_mfma_f32_16x16x32_bf16(a[i], b[j], acc[i][j], 0, 0, 0);
    __syncthreads();
  }

  const int rq = (lane >> 4) * 4;
  #pragma unroll
  for (int i = 0; i < 4; ++i) {
    #pragma unroll
    for (int j = 0; j < 4; ++j) {
      long col = brow0 + wn + j * 16 + fr;
      float bv = bias[col];
      #pragma unroll
      for (int r = 0; r < 4; ++r) {
        long row = arow0 + wm + i * 16 + rq + r;
        float v = acc[i][j][r] + bv;
        if (MODE == 0) {
          ((bf16_t*)outp)[row * N + col] = (bf16_t)v;
        } else if (MODE == 1) {
          ((float*)outp)[row * N + col] = v + resid[row * N + col];
        } else {
          float g = 0.5f * v * (1.0f + erff(v * 0.70710678118654752f));
          ((bf16_t*)outp)[row * N + col] = (bf16_t)g;
        }
      }
    }
  }
}

// ---------------------------------------------------------------- q softmax (in-place, per (row, head) over 64)
__global__ __launch_bounds__(256) void qsoftmax(bf16_t* __restrict__ qkv) {
  long r = blockIdx.x;
  int t = threadIdx.x, h = t >> 4, l = t & 15;
  bf16_t* p = qkv + r * 3072 + h * 64 + l * 4;
  bf16x4 v4 = *(const bf16x4*)p;
  float v0 = v4[0], v1 = v4[1], v2 = v4[2], v3 = v4[3];
  float m = fmaxf(fmaxf(v0, v1), fmaxf(v2, v3));
  #pragma unroll
  for (int o = 8; o >= 1; o >>= 1) m = fmaxf(m, __shfl_xor(m, o));
  float e0 = __expf(v0 - m), e1 = __expf(v1 - m), e2 = __expf(v2 - m), e3 = __expf(v3 - m);
  float s = e0 + e1 + e2 + e3;
  #pragma unroll
  for (int o = 8; o >= 1; o >>= 1) s += __shfl_xor(s, o);
  float inv = 1.0f / s;
  bf16x4 o4;
  o4[0] = (bf16_t)(e0 * inv); o4[1] = (bf16_t)(e1 * inv);
  o4[2] = (bf16_t)(e2 * inv); o4[3] = (bf16_t)(e3 * inv);
  *(bf16x4*)p = o4;
}

// ---------------------------------------------------------------- k column-softmax stats (online max/sum partials)
__global__ __launch_bounds__(256) void kstats_partial(const bf16_t* __restrict__ qkv,
                                                      float2* __restrict__ part) {
  int bh = blockIdx.x, ch = blockIdx.y;
  int b = bh >> 4, h = bh & 15;
  int t = threadIdx.x, d = t & 63, sr = t >> 6;
  const bf16_t* kp = qkv + (long)b * SS * 3072 + 1024 + h * 64 + d;
  float m = -INFINITY, sum = 0.f;
  for (int s = ch * 512 + sr; s < ch * 512 + 512; s += 4) {
    float v = (float)kp[(long)s * 3072];
    float nm = fmaxf(m, v);
    sum = sum * __expf(m - nm) + __expf(v - nm);
    m = nm;
  }
  __shared__ float2 red[4][64];
  red[sr][d] = make_float2(m, sum);
  __syncthreads();
  if (t < 64) {
    float2 a = red[0][t];
    #pragma unroll
    for (int i = 1; i < 4; ++i) {
      float2 p = red[i][t];
      float nm = fmaxf(a.x, p.x);
      a.y = a.y * __expf(a.x - nm) + p.y * __expf(p.x - nm);
      a.x = nm;
    }
    part[(long)(bh * 8 + ch) * 64 + t] = a;
  }
}

__global__ void kstats_merge(const float2* __restrict__ part, float2* __restrict__ stat) {
  int bh = blockIdx.x, d = threadIdx.x;  // 64 threads
  float m = -INFINITY, s = 0.f;
  #pragma unroll
  for (int c = 0; c < 8; ++c) {
    float2 p = part[(long)(bh * 8 + c) * 64 + d];
    float nm = fmaxf(m, p.x);
    s = s * __expf(m - nm) + p.y * __expf(p.x - nm);
    m = nm;
  }
  stat[bh * 64 + d] = make_float2(m, 1.0f / s);
}

// ---------------------------------------------------------------- kv = sum_s softmax_k[s,d] * v[s,e]  (partials over s-chunks)
__global__ __launch_bounds__(256) void kv_partial(const bf16_t* __restrict__ qkv,
                                                  const float2* __restrict__ stat,
                                                  float* __restrict__ kvp) {
  int bh = blockIdx.x, ch = blockIdx.y;
  int b = bh >> 4, h = bh & 15;
  int t = threadIdx.x;
  __shared__ float  Kexp[64][65];
  __shared__ bf16_t Vs[64][72];
  __shared__ float  kmaxs[64], kinvs[64];
  if (t < 64) { float2 p = stat[bh * 64 + t]; kmaxs[t] = p.x; kinvs[t] = p.y; }
  int rowl = t >> 2, c0 = (t & 3) * 16;
  int dd = t >> 2, e0 = (t & 3) * 16;
  float acc[16] = {};
  for (int sb = 0; sb < 8; ++sb) {
    long s = (long)ch * 512 + sb * 64 + rowl;
    const bf16_t* base = qkv + ((long)b * SS + s) * 3072 + h * 64;
    bf16x8 k0 = *(const bf16x8*)(base + 1024 + c0);
    bf16x8 k1 = *(const bf16x8*)(base + 1024 + c0 + 8);
    bf16x8 v0 = *(const bf16x8*)(base + 2048 + c0);
    bf16x8 v1 = *(const bf16x8*)(base + 2048 + c0 + 8);
    __syncthreads();
    #pragma unroll
    for (int j = 0; j < 8; ++j) {
      Kexp[rowl][c0 + j]     = __expf((float)k0[j] - kmaxs[c0 + j]) * kinvs[c0 + j];
      Kexp[rowl][c0 + 8 + j] = __expf((float)k1[j] - kmaxs[c0 + 8 + j]) * kinvs[c0 + 8 + j];
    }
    *(bf16x8*)&Vs[rowl][c0]     = v0;
    *(bf16x8*)&Vs[rowl][c0 + 8] = v1;
    __syncthreads();
    for (int ls = 0; ls < 64; ++ls) {
      float kd = Kexp[ls][dd];
      bf16x8 va = *(const bf16x8*)&Vs[ls][e0];
      bf16x8 vb = *(const bf16x8*)&Vs[ls][e0 + 8];
      #pragma unroll
      for (int j = 0; j < 8; ++j) {
        acc[j]     += kd * (float)va[j];
        acc[j + 8] += kd * (float)vb[j];
      }
    }
  }
  float* dst = kvp + (long)(bh * 8 + ch) * 4096 + dd * 64 + e0;
  #pragma unroll
  for (int j = 0; j < 16; ++j) dst[j] = acc[j];
}

// reduce partials, store TRANSPOSED bf16: kvT[bh][e][d]
__global__ void kv_reduce(const float* __restrict__ kvp, bf16_t* __restrict__ kvT) {
  int bh = blockIdx.x, t = threadIdx.x;
  for (int p = t; p < 4096; p += 256) {
    int d = p >> 6, e = p & 63;
    float s = 0.f;
    #pragma unroll
    for (int c = 0; c < 8; ++c) s += kvp[(long)(bh * 8 + c) * 4096 + p];
    kvT[(long)bh * 4096 + e * 64 + d] = (bf16_t)s;
  }
}

// ---------------------------------------------------------------- out[s,e] = q_sm[s,:] @ kv[:,e]  via MFMA, per (b,h)
__global__ __launch_bounds__(256) void attn_apply(const bf16_t* __restrict__ qkv,
                                                  const bf16_t* __restrict__ kvT,
                                                  bf16_t* __restrict__ attn) {
  int bh = blockIdx.x, sc = blockIdx.y;
  int b = bh >> 4, h = bh & 15;
  int t = threadIdx.x, lane = t & 63, w = t >> 6;
  __shared__ bf16_t kvs[64 * 64];
  for (int i = t * 8; i < 4096; i += 256 * 8)
    *(bf16x8*)&kvs[i] = *(const bf16x8*)(kvT + (long)bh * 4096 + i);
  __syncthreads();
  int fr = lane & 15, kq = (lane >> 4) * 8;
  long qrow = (long)b * SS + sc * 128 + w * 32;
  f32x4 acc[2][4] = {};
  #pragma unroll
  for (int kk = 0; kk < 2; ++kk) {
    bf16x8 a0 = *(const bf16x8*)(qkv + (qrow + fr) * 3072      + h * 64 + kk * 32 + kq);
    bf16x8 a1 = *(const bf16x8*)(qkv + (qrow + 16 + fr) * 3072 + h * 64 + kk * 32 + kq);
    #pragma unroll
    for (int j = 0; j < 4; ++j) {
      bf16x8 bfr = *(const bf16x8*)&kvs[(j * 16 + fr) * 64 + kk * 32 + kq];
      acc[0][j] = __builtin_amdgcn_mfma_f32_16x16x32_bf16(a0, bfr, acc[0][j], 0, 0, 0);
      acc[1][j] = __builtin_amdgcn_mfma_f32_16x16x32_bf16(a1, bfr, acc[1][j], 0, 0, 0);
    }
  }
  int rq = (lane >> 4) * 4;
  #pragma unroll
  for (int i = 0; i < 2; ++i)
    #pragma unroll
    for (int j = 0; j < 4; ++j)
      #pragma unroll
      for (int r = 0; r < 4; ++r)
        attn[(qrow + i * 16 + rq + r) * 1024 + h * 64 + j * 16 + fr] = (bf16_t)acc[i][j][r];
}

// ---------------------------------------------------------------- launch
extern "C" void kernel_launch(void* const* d_in, const int* in_sizes, int n_in,
                              void* d_out, int out_size, void* d_ws, size_t ws_size,
                              hipStream_t stream) {
  (void)in_sizes; (void)n_in; (void)out_size; (void)ws_size;
  const float* x      = (const float*)d_in[0];
  const float* w_qkv  = (const float*)d_in[1];
  const float* b_qkv  = (const float*)d_in[2];
  const float* w_out  = (const float*)d_in[3];
  const float* b_out  = (const float*)d_in[4];
  const float* w_ffn1 = (const float*)d_in[5];
  const float* b_ffn1 = (const float*)d_in[6];
  const float* w_ffn2 = (const float*)d_in[7];
  const float* b_ffn2 = (const float*)d_in[8];
  const float* g1     = (const float*)d_in[9];
  const float* be1    = (const float*)d_in[10];
  const float* g2     = (const float*)d_in[11];
  const float* be2    = (const float*)d_in[12];

  // ---------------- workspace layout (total 168,591,360 B ≈ 160.8 MB) ----------------
  // Liveness: QKV dead after attn_apply. Y (f32 residual) lives in d_out: out-proj
  // writes it, ln2 reads it, ffn2 overwrites it with the final output (stream-ordered,
  // fully rewritten every call). FFN runs in two 8192-row chunks so its GACT scratch
  // is 64 MB and shares the BIG region with the (then-dead) QKV.
  char* ws = (char*)d_ws;
  constexpr size_t WT_QKV_OFF  = 0;                                   // 3072x1024 bf16 = 6291456
  constexpr size_t WT_OUT_OFF  = WT_QKV_OFF  + 6291456;               // 1024x1024 bf16 = 2097152
  constexpr size_t WT_FFN1_OFF = WT_OUT_OFF  + 2097152;               // 4096x1024 bf16 = 8388608
  constexpr size_t WT_FFN2_OFF = WT_FFN1_OFF + 8388608;               // 1024x4096 bf16 = 8388608
  constexpr size_t KSTATP_OFF  = WT_FFN2_OFF + 8388608;               // 512*64*8     = 262144
  constexpr size_t KSTAT_OFF   = KSTATP_OFF  + 262144;                // 64*64*8      = 32768
  constexpr size_t KVP_OFF     = KSTAT_OFF   + 32768;                 // 512*4096*4   = 8388608
  constexpr size_t KVT_OFF     = KVP_OFF     + 8388608;               // 64*4096*2    = 524288
  constexpr size_t ACT1_OFF    = KVT_OFF     + 524288;                // 16384*1024*2 = 33554432 (ln1/attn_cat/ln2)
  constexpr size_t BIG_OFF     = ACT1_OFF    + 33554432;              // max(qkv 96MB, gact-chunk 64MB) = 100663296

  bf16_t* WT_QKV  = (bf16_t*)(ws + WT_QKV_OFF);
  bf16_t* WT_OUT  = (bf16_t*)(ws + WT_OUT_OFF);
  bf16_t* WT_FFN1 = (bf16_t*)(ws + WT_FFN1_OFF);
  bf16_t* WT_FFN2 = (bf16_t*)(ws + WT_FFN2_OFF);
  float2* KSTATP  = (float2*)(ws + KSTATP_OFF);
  float2* KSTAT   = (float2*)(ws + KSTAT_OFF);
  float*  KVP     = (float*) (ws + KVP_OFF);
  bf16_t* KVT     = (bf16_t*)(ws + KVT_OFF);
  bf16_t* ACT1    = (bf16_t*)(ws + ACT1_OFF);
  bf16_t* QKV     = (bf16_t*)(ws + BIG_OFF);   // 16384*3072 bf16 (96 MB)
  bf16_t* GACT    = (bf16_t*)(ws + BIG_OFF);   // 8192*4096 bf16 (64 MB) — after QKV dead
  float*  Y       = (float*)  d_out;           // 16384*1024 f32 (64 MB) — Y = x + attn_out

  // weights -> bf16 transposed (N x K)
  wtrans<<<dim3(3072 / 32, 1024 / 32), dim3(32, 8), 0, stream>>>(w_qkv,  WT_QKV,  1024, 3072);
  wtrans<<<dim3(1024 / 32, 1024 / 32), dim3(32, 8), 0, stream>>>(w_out,  WT_OUT,  1024, 1024);
  wtrans<<<dim3(4096 / 32, 1024 / 32), dim3(32, 8), 0, stream>>>(w_ffn1, WT_FFN1, 1024, 4096);
  wtrans<<<dim3(1024 / 32, 4096 / 32), dim3(32, 8), 0, stream>>>(w_ffn2, WT_FFN2, 4096, 1024);

  // ln1(x) -> ACT1
  ln_kernel<<<NROWS, 256, 0, stream>>>(x, g1, be1, ACT1);

  // qkv = ln1 @ WqkvT + b  (bf16)
  gemm_bt<0><<<dim3(3072 / 128, NROWS / 128), 256, 0, stream>>>(ACT1, WT_QKV, b_qkv, nullptr, QKV, NROWS, 3072, 1024);

  // q softmax in-place
  qsoftmax<<<NROWS, 256, 0, stream>>>(QKV);

  // k column softmax stats
  kstats_partial<<<dim3(64, 8), 256, 0, stream>>>(QKV, KSTATP);
  kstats_merge<<<64, 64, 0, stream>>>(KSTATP, KSTAT);

  // kv einsum (softmax applied on the fly), then reduce to kvT bf16
  kv_partial<<<dim3(64, 8), 256, 0, stream>>>(QKV, KSTAT, KVP);
  kv_reduce<<<64, 256, 0, stream>>>(KVP, KVT);

  // attn out per head -> ACT1 (attn_cat)
  attn_apply<<<dim3(64, SS / 128), 256, 0, stream>>>(QKV, KVT, ACT1);

  // y = x + attn_cat @ WoutT + b  (f32) -> d_out  (QKV now dead)
  gemm_bt<1><<<dim3(1024 / 128, NROWS / 128), 256, 0, stream>>>(ACT1, WT_OUT, b_out, x, Y, NROWS, 1024, 1024);

  // ln2(y) -> ACT1
  ln_kernel<<<NROWS, 256, 0, stream>>>(Y, g2, be2, ACT1);

  // FFN in two 8192-row chunks; GACT (64 MB) reused per chunk; ffn2 overwrites d_out
  for (int c = 0; c < 2; ++c) {
    const long r0 = (long)c * 8192;
    gemm_bt<2><<<dim3(4096 / 128, 8192 / 128), 256, 0, stream>>>(
        ACT1 + r0 * 1024, WT_FFN1, b_ffn1, nullptr, GACT, 8192, 4096, 1024);
    gemm_bt<1><<<dim3(1024 / 128, 8192 / 128), 256, 0, stream>>>(
        GACT, WT_FFN2, b_ffn2, x + r0 * 1024, (float*)d_out + r0 * 1024, 8192, 1024, 4096);
  }
}